// Round 7
// baseline (648.115 us; speedup 1.0000x reference)
//
#include <hip/hip_runtime.h>
#include <hip/hip_bf16.h>

// ---------------- problem constants ----------------
#define B_    128
#define NN    2000
#define C_    256
#define E_    64000
#define CIN   64
#define ROWST 2064   // CIN + NN
#define CEMB  128
#define HAZ1  512
#define HAZ2  256
#define FUSD  640    // CEMB + 2*C_

typedef unsigned short u16;
typedef __attribute__((ext_vector_type(8))) short short8;
typedef __attribute__((ext_vector_type(8))) unsigned short ush8;
typedef __attribute__((ext_vector_type(4))) float f32x4;

// ---------------- workspace layout (bytes) ----------------
static constexpr size_t OFF_DEGO = 0;        // int[2000]
static constexpr size_t OFF_DEGI = 8000;     // int[2000]
static constexpr size_t OFF_CUR  = 16000;    // int[2000]
static constexpr size_t OFF_WOUT = 24000;    // float[2000]
static constexpr size_t OFF_WIN  = 32000;    // float[2000]
static constexpr size_t OFF_IOFF = 40000;    // int[2001] (padded)
static constexpr size_t OFF_CSRC = 48192;    // int[64000]
static constexpr size_t OFF_CSRW = 304192;   // float[64000]
static constexpr size_t OFF_HG   = 560192;   // float[128*512]           -> 822336
static constexpr size_t OFF_EMB  = 822336;   // float[128*128]           -> 887872
static constexpr size_t OFF_H1   = 887872;   // float[128*512]           -> 1150016
static constexpr size_t OFF_H2   = 1150016;  // float[128*256]           -> 1281088
static constexpr size_t OFF_PSUM = 1281088;  // float[128*256]           -> 1412160
static constexpr size_t OFF_PMAX = 1412160;  // float[128*256]           -> 1543232
static constexpr size_t OFF_A    = 1543232;  // float[128*2000]          -> 2567232
static constexpr size_t OFF_WT1H = 2567232;  // u16[256*256]             -> 2698304
static constexpr size_t OFF_WT2H = 2829376;  //                          -> 2960448
static constexpr size_t OFF_XBUF = 4194304;  // xB bf16 [CB*NN*C_], then xA bf16 [CB*NN*C_]

// ---------------- bf16 helpers (RNE) ----------------
__device__ __forceinline__ u16 f2bf(float f) {
    union { float f; unsigned u; } v; v.f = f;
    unsigned u = v.u;
    unsigned r = (u + 0x7FFFu + ((u >> 16) & 1u)) >> 16;
    return (u16)r;
}
__device__ __forceinline__ float bf2f(u16 h) {
    union { unsigned u; float f; } v; v.u = ((unsigned)h) << 16;
    return v.f;
}

// ---------------- utility ----------------
__global__ void k_zero(float* p, int n) {
    int i = blockIdx.x * 256 + threadIdx.x;
    if (i < n) p[i] = 0.f;
}

__global__ void k_deg(const int* __restrict__ src, const int* __restrict__ dst,
                      int* __restrict__ dego, int* __restrict__ degi) {
    int e = blockIdx.x * 256 + threadIdx.x;
    if (e < E_) {
        atomicAdd(&dego[src[e]], 1);
        atomicAdd(&degi[dst[e]], 1);
    }
}

__global__ void k_norm(const int* __restrict__ dego, const int* __restrict__ degi,
                       float* __restrict__ wout, float* __restrict__ win) {
    int n = blockIdx.x * 256 + threadIdx.x;
    if (n < NN) {
        wout[n] = rsqrtf(fmaxf((float)dego[n], 1.f));
        win[n]  = rsqrtf(fmaxf((float)degi[n], 1.f));
    }
}

// exclusive scan of in-degrees -> in_off[0..NN], one block of 512 threads
__global__ void k_scan(const int* __restrict__ degi, int* __restrict__ ioff) {
    __shared__ int part[512];
    int t = threadIdx.x;
    int base = t * 4;
    int v[4]; int s = 0;
#pragma unroll
    for (int i = 0; i < 4; i++) {
        int idx = base + i;
        v[i] = (idx < NN) ? degi[idx] : 0;
        s += v[i];
    }
    part[t] = s;
    __syncthreads();
    for (int o = 1; o < 512; o <<= 1) {
        int x = 0;
        if (t >= o) x = part[t - o];
        __syncthreads();
        part[t] += x;
        __syncthreads();
    }
    int run = (t == 0) ? 0 : part[t - 1];
#pragma unroll
    for (int i = 0; i < 4; i++) {
        int idx = base + i;
        if (idx <= NN) ioff[idx] = run;
        run += v[i];
    }
}

__global__ void k_fill(const int* __restrict__ src, const int* __restrict__ dst,
                       const float* __restrict__ wout, const float* __restrict__ win,
                       const int* __restrict__ ioff, int* __restrict__ cursor,
                       int* __restrict__ csrc, float* __restrict__ csrw) {
    int e = blockIdx.x * 256 + threadIdx.x;
    if (e < E_) {
        int d = dst[e];
        int s = src[e];
        int p = atomicAdd(&cursor[d], 1);
        int i = ioff[d] + p;
        csrc[i] = s;
        csrw[i] = wout[s] * win[d];
    }
}

// transpose W (256x256) into bf16: T[n*256+k] = bf16(W[k*256+n])
__global__ __launch_bounds__(256) void k_prepw(const float* __restrict__ W,
                                               u16* __restrict__ Th) {
    int n = blockIdx.x, k = threadIdx.x;
    Th[n * 256 + k] = f2bf(W[(size_t)k * 256 + n]);
}

// scalar graph conv of the input node feature: a[b,n] = sum_e csrw * inp_x[b,src]
__global__ __launch_bounds__(64) void k_agg_scalar(
        const float* __restrict__ inp, const int* __restrict__ ioff,
        const int* __restrict__ csrc, const float* __restrict__ csrw,
        float* __restrict__ a) {
    int n = blockIdx.x * 64 + threadIdx.x;
    int b = blockIdx.y;
    if (n >= NN) return;
    const float* row = inp + (size_t)b * ROWST + CIN;
    int e0 = ioff[n], e1 = ioff[n + 1];
    float acc = 0.f;
    for (int i = e0; i < e1; i++) acc += csrw[i] * row[csrc[i]];
    a[(size_t)b * NN + n] = acc;
}

// layer-0 pooling straight from a: x0[b,n,c] = relu(a*W0[c]+b0[c])
__global__ __launch_bounds__(256) void k_pool0(
        const float* __restrict__ a, const float* __restrict__ W0,
        const float* __restrict__ b0, float* __restrict__ hg) {
    int b = blockIdx.x, c = threadIdx.x;
    float w0c = W0[c], b0c = b0[c];
    const float* ab = a + (size_t)b * NN;
    float s = 0.f, mx = 0.f;
    for (int n = 0; n < NN; n++) {
        float v = fmaxf(fmaf(ab[n], w0c, b0c), 0.f);
        s += v;
        mx = fmaxf(mx, v);
    }
    hg[(size_t)b * 512 + c]       += s * (1.f / (float)NN);
    hg[(size_t)b * 512 + 256 + c] += mx;
}

// fused layer-0-expand + layer-1 aggregation, bf16 out, edge-loop unroll x2.
// wave serves 2 batch elems: lanes 0-31 -> bl=2*bp, lanes 32-63 -> 2*bp+1.
__global__ __launch_bounds__(64) void k_agg_l1(
        const float* __restrict__ a, const int* __restrict__ ioff,
        const int* __restrict__ csrc, const float* __restrict__ csrw,
        const float* __restrict__ W0, const float* __restrict__ b0,
        u16* __restrict__ xout, int b0g) {
    int n = blockIdx.x, bp = blockIdx.y, t = threadIdx.x;
    int half = t >> 5, c8 = (t & 31) * 8;
    int bl = bp * 2 + half;
    int e0 = ioff[n], e1 = ioff[n + 1];
    const float* ab = a + (size_t)(b0g + bl) * NN;
    float w[8], bb[8], acca[8] = {}, accb[8] = {};
#pragma unroll
    for (int j = 0; j < 8; j++) { w[j] = W0[c8 + j]; bb[j] = b0[c8 + j]; }
    int i = e0;
    for (; i + 2 <= e1; i += 2) {
        float a0 = ab[csrc[i]],     we0 = csrw[i];
        float a1 = ab[csrc[i + 1]], we1 = csrw[i + 1];
#pragma unroll
        for (int j = 0; j < 8; j++) {
            acca[j] = fmaf(fmaxf(fmaf(a0, w[j], bb[j]), 0.f), we0, acca[j]);
            accb[j] = fmaf(fmaxf(fmaf(a1, w[j], bb[j]), 0.f), we1, accb[j]);
        }
    }
    if (i < e1) {
        float a0 = ab[csrc[i]], we0 = csrw[i];
#pragma unroll
        for (int j = 0; j < 8; j++)
            acca[j] = fmaf(fmaxf(fmaf(a0, w[j], bb[j]), 0.f), we0, acca[j]);
    }
    ush8 o;
#pragma unroll
    for (int j = 0; j < 8; j++) o[j] = f2bf(acca[j] + accb[j]);
    *reinterpret_cast<ush8*>(&xout[((size_t)bl * NN + n) * C_ + c8]) = o;
}

// layer-2 aggregation, bf16 in/out, 2 bl per wave, 16B/lane gathers, unroll x2.
// XCD-locality swizzle (verified round 3: over-fetch eliminated).
__global__ __launch_bounds__(64) void k_agg_bf(
        const u16* __restrict__ xin, const int* __restrict__ ioff,
        const int* __restrict__ csrc, const float* __restrict__ csrw,
        u16* __restrict__ xout, int QBH) {
    int l = blockIdx.x + NN * blockIdx.y;   // HW linear workgroup id (x fastest)
    int xcd = l & 7, slot = l >> 3;
    int q = slot / NN;
    int bp = xcd * QBH + q;
    int n = slot - q * NN;
    int t = threadIdx.x;
    int half = t >> 5, c8 = (t & 31) * 8;
    int bl = bp * 2 + half;
    int e0 = ioff[n], e1 = ioff[n + 1];
    const u16* xb = xin + (size_t)bl * NN * C_ + c8;
    float acca[8] = {}, accb[8] = {};
    int i = e0;
    for (; i + 2 <= e1; i += 2) {
        int s0 = csrc[i];     float w0 = csrw[i];
        int s1 = csrc[i + 1]; float w1 = csrw[i + 1];
        ush8 v0 = *reinterpret_cast<const ush8*>(&xb[(size_t)s0 * C_]);
        ush8 v1 = *reinterpret_cast<const ush8*>(&xb[(size_t)s1 * C_]);
#pragma unroll
        for (int j = 0; j < 8; j++) {
            acca[j] = fmaf(bf2f(v0[j]), w0, acca[j]);
            accb[j] = fmaf(bf2f(v1[j]), w1, accb[j]);
        }
    }
    if (i < e1) {
        int s0 = csrc[i]; float w0 = csrw[i];
        ush8 v0 = *reinterpret_cast<const ush8*>(&xb[(size_t)s0 * C_]);
#pragma unroll
        for (int j = 0; j < 8; j++) acca[j] = fmaf(bf2f(v0[j]), w0, acca[j]);
    }
    ush8 o;
#pragma unroll
    for (int j = 0; j < 8; j++) o[j] = f2bf(acca[j] + accb[j]);
    *reinterpret_cast<ush8*>(&xout[((size_t)bl * NN + n) * C_ + c8]) = o;
}

// ---------------- MFMA GEMM (bf16 A, bf16 W, 1 pass) with fused pooling ----
// C = relu(A @ W + bias); pool (sum,max) per (bl, col) into psum/pmax atomics.
// OUT: 0 = pool only (no C write), 1 = write C as bf16.
#define GM 128
#define GN 128
#define GK 32
#define LDP 40   // padded u16 row stride (80 B) -> 2-way banks max on ds_read_b128

template<int OUT>
__global__ __launch_bounds__(256) void k_gemm_mfma(
        const u16* __restrict__ Abf, const u16* __restrict__ WTh,
        const float* __restrict__ bias,
        u16* __restrict__ Cbf, float* __restrict__ psum, float* __restrict__ pmax) {
    __shared__ u16 Ah[GM * LDP];
    __shared__ u16 Bh[GN * LDP];
    __shared__ float lsum[2][2][GN];
    __shared__ float lmax[2][2][GN];
    int tid  = threadIdx.x;
    int lane = tid & 63, wave = tid >> 6;
    int wm = wave >> 1, wn = wave & 1;
    int n0 = blockIdx.x * GN;
    int m0 = blockIdx.y * GM;
    int blk = lane >> 4, rr = lane & 15;

    f32x4 acc[4][4] = {};

    for (int k0 = 0; k0 < 256; k0 += GK) {
        // stage A + B: each 128 rows x 32 k bf16 = 512 x 16B segs, 2/thread
#pragma unroll
        for (int q = 0; q < 2; q++) {
            int f = tid + 256 * q;
            int row = f >> 2, seg = f & 3;
            ush8 va = *reinterpret_cast<const ush8*>(
                &Abf[(size_t)(m0 + row) * 256 + k0 + seg * 8]);
            ush8 vb = *reinterpret_cast<const ush8*>(
                &WTh[(size_t)(n0 + row) * 256 + k0 + seg * 8]);
            *reinterpret_cast<ush8*>(&Ah[row * LDP + seg * 8]) = va;
            *reinterpret_cast<ush8*>(&Bh[row * LDP + seg * 8]) = vb;
        }
        __syncthreads();

        short8 af[4], bf[4];
#pragma unroll
        for (int mr = 0; mr < 4; mr++)
            af[mr] = *reinterpret_cast<const short8*>(
                &Ah[(wm * 64 + mr * 16 + rr) * LDP + blk * 8]);
#pragma unroll
        for (int nr = 0; nr < 4; nr++)
            bf[nr] = *reinterpret_cast<const short8*>(
                &Bh[(wn * 64 + nr * 16 + rr) * LDP + blk * 8]);
#pragma unroll
        for (int mr = 0; mr < 4; mr++)
#pragma unroll
            for (int nr = 0; nr < 4; nr++)
                acc[mr][nr] = __builtin_amdgcn_mfma_f32_16x16x32_bf16(
                    af[mr], bf[nr], acc[mr][nr], 0, 0, 0);
        __syncthreads();
    }

    // epilogue: bias + relu, optional bf16 store, fused (sum,max) pool
    int bl0   = m0 / NN;
    int split = (bl0 + 1) * NN - m0;   // local rows >= split belong to bl0+1

    float s_lo[4] = {}, s_hi[4] = {}, m_lo[4] = {}, m_hi[4] = {};
#pragma unroll
    for (int nr = 0; nr < 4; nr++) {
        int col = n0 + wn * 64 + nr * 16 + rr;
        float bs = bias[col];
#pragma unroll
        for (int mr = 0; mr < 4; mr++) {
            int rl = wm * 64 + mr * 16 + blk * 4;
#pragma unroll
            for (int j = 0; j < 4; j++) {
                float v = fmaxf(acc[mr][nr][j] + bs, 0.f);
                if (OUT == 1)
                    Cbf[(size_t)(m0 + rl + j) * 256 + col] = f2bf(v);
                bool second = (rl + j) >= split;
                s_lo[nr] += second ? 0.f : v;
                s_hi[nr] += second ? v : 0.f;
                m_lo[nr] = second ? m_lo[nr] : fmaxf(m_lo[nr], v);
                m_hi[nr] = second ? fmaxf(m_hi[nr], v) : m_hi[nr];
            }
        }
    }
#pragma unroll
    for (int nr = 0; nr < 4; nr++) {
        s_lo[nr] += __shfl_xor(s_lo[nr], 16); s_lo[nr] += __shfl_xor(s_lo[nr], 32);
        s_hi[nr] += __shfl_xor(s_hi[nr], 16); s_hi[nr] += __shfl_xor(s_hi[nr], 32);
        m_lo[nr] = fmaxf(m_lo[nr], __shfl_xor(m_lo[nr], 16));
        m_lo[nr] = fmaxf(m_lo[nr], __shfl_xor(m_lo[nr], 32));
        m_hi[nr] = fmaxf(m_hi[nr], __shfl_xor(m_hi[nr], 16));
        m_hi[nr] = fmaxf(m_hi[nr], __shfl_xor(m_hi[nr], 32));
    }
    if (lane < 16) {
#pragma unroll
        for (int nr = 0; nr < 4; nr++) {
            int cl = wn * 64 + nr * 16 + lane;
            lsum[0][wm][cl] = s_lo[nr];
            lsum[1][wm][cl] = s_hi[nr];
            lmax[0][wm][cl] = m_lo[nr];
            lmax[1][wm][cl] = m_hi[nr];
        }
    }
    __syncthreads();
    {
        int seg = tid >> 7, cl = tid & 127;
        if (!(seg == 1 && split >= GM)) {
            float s = lsum[seg][0][cl] + lsum[seg][1][cl];
            float m = fmaxf(lmax[seg][0][cl], lmax[seg][1][cl]);
            int blx = bl0 + seg;
            atomicAdd(&psum[blx * C_ + n0 + cl], s);
            atomicMax((unsigned int*)&pmax[blx * C_ + n0 + cl], __float_as_uint(m));
        }
    }
}

// combine fused-pool results into hg, then reset psum/pmax for next use
__global__ __launch_bounds__(256) void k_pool_combine(
        float* __restrict__ psum, float* __restrict__ pmax,
        float* __restrict__ hg, int b0g) {
    int bl = blockIdx.x, c = threadIdx.x;
    float s = psum[bl * C_ + c];
    float m = pmax[bl * C_ + c];
    psum[bl * C_ + c] = 0.f;
    pmax[bl * C_ + c] = 0.f;
    size_t b = b0g + bl;
    hg[b * 512 + c]       += s * (1.f / (float)NN);
    hg[b * 512 + 256 + c] += m;
}

__global__ __launch_bounds__(128) void k_embed(
        const float* __restrict__ inp, const float* __restrict__ We,
        float* __restrict__ emb) {
    int b = blockIdx.x, c = threadIdx.x;
    const float* row = inp + (size_t)b * ROWST;
    float a = 0.f;
    for (int k = 0; k < CIN; k++) a += row[k] * We[k * CEMB + c];
    emb[b * CEMB + c] = fmaxf(a, 0.f);
}

__global__ __launch_bounds__(512) void k_mlp1(
        const float* __restrict__ emb, const float* __restrict__ hg,
        const float* __restrict__ Wh1, const float* __restrict__ bh1,
        float* __restrict__ h1) {
    __shared__ float fus[FUSD];
    int b = blockIdx.x, j = threadIdx.x;
    if (j < CEMB) fus[j] = emb[b * CEMB + j];
    fus[CEMB + j] = hg[(size_t)b * 512 + j];
    __syncthreads();
    float a = bh1[j];
    for (int k = 0; k < FUSD; k++) a += fus[k] * Wh1[(size_t)k * HAZ1 + j];
    h1[(size_t)b * HAZ1 + j] = fmaxf(a, 0.f);
}

__global__ __launch_bounds__(256) void k_mlp2(
        const float* __restrict__ h1, const float* __restrict__ Wh2,
        const float* __restrict__ bh2, float* __restrict__ h2) {
    __shared__ float f2[HAZ1];
    int b = blockIdx.x, j = threadIdx.x;
    f2[j]       = h1[(size_t)b * HAZ1 + j];
    f2[256 + j] = h1[(size_t)b * HAZ1 + 256 + j];
    __syncthreads();
    float a = bh2[j];
    for (int k = 0; k < HAZ1; k++) a += f2[k] * Wh2[(size_t)k * HAZ2 + j];
    h2[(size_t)b * HAZ2 + j] = fmaxf(a, 0.f);
}

__global__ __launch_bounds__(256) void k_out(
        const float* __restrict__ h2, const float* __restrict__ Wh3,
        float* __restrict__ out) {
    __shared__ float red[256];
    int b = blockIdx.x, t = threadIdx.x;
    red[t] = h2[(size_t)b * HAZ2 + t] * Wh3[t];
    __syncthreads();
    for (int o = 128; o > 0; o >>= 1) {
        if (t < o) red[t] += red[t + o];
        __syncthreads();
    }
    if (t == 0) out[b] = red[0];
}

// ---------------- launch ----------------
extern "C" void kernel_launch(void* const* d_in, const int* in_sizes, int n_in,
                              void* d_out, int out_size, void* d_ws, size_t ws_size,
                              hipStream_t stream) {
    const float* inp = (const float*)d_in[0];
    const int*   src = (const int*)d_in[1];
    const int*   dst = (const int*)d_in[2];
    const float* W0  = (const float*)d_in[3];
    const float* b0  = (const float*)d_in[4];
    const float* W1  = (const float*)d_in[5];
    const float* b1  = (const float*)d_in[6];
    const float* W2  = (const float*)d_in[7];
    const float* b2  = (const float*)d_in[8];
    const float* We  = (const float*)d_in[9];
    const float* Wh1 = (const float*)d_in[10];
    const float* bh1 = (const float*)d_in[11];
    const float* Wh2 = (const float*)d_in[12];
    const float* bh2 = (const float*)d_in[13];
    const float* Wh3 = (const float*)d_in[14];
    float* out = (float*)d_out;

    char* ws = (char*)d_ws;
    int*   dego = (int*)(ws + OFF_DEGO);
    int*   degi = (int*)(ws + OFF_DEGI);
    int*   cur  = (int*)(ws + OFF_CUR);
    float* wout = (float*)(ws + OFF_WOUT);
    float* win  = (float*)(ws + OFF_WIN);
    int*   ioff = (int*)(ws + OFF_IOFF);
    int*   csrc = (int*)(ws + OFF_CSRC);
    float* csrw = (float*)(ws + OFF_CSRW);
    float* hg   = (float*)(ws + OFF_HG);
    float* emb  = (float*)(ws + OFF_EMB);
    float* h1   = (float*)(ws + OFF_H1);
    float* h2   = (float*)(ws + OFF_H2);
    float* psum = (float*)(ws + OFF_PSUM);
    float* pmax = (float*)(ws + OFF_PMAX);
    float* avec = (float*)(ws + OFF_A);
    u16*   wt1h = (u16*)(ws + OFF_WT1H);
    u16*   wt2h = (u16*)(ws + OFF_WT2H);

    // ---- choose batch-chunk size CB ----
    // need = OFF_XBUF + CB * 2 * (NN*C_*2)  (two bf16 x buffers)
    // CB multiple of 16 (CBH%8==0 for the agg swizzle; CB*NN%GM==0).
    const size_t perb = (size_t)NN * C_ * 4;
    int CB = 128;
    while (CB > 16 && OFF_XBUF + (size_t)CB * perb > ws_size) CB >>= 1;
    int nchunk = B_ / CB;
    int CBH = CB / 2;
    int QBH = CBH / 8;

    u16* xB   = (u16*)(ws + OFF_XBUF);                              // agg out (GEMM A)
    u16* xAbf = (u16*)(ws + OFF_XBUF + (size_t)CB * NN * C_ * 2);   // bf16 x1

    // zeros: deg counters (6000 ints), hg, psum+pmax (contiguous 65536 floats)
    k_zero<<<dim3((6000 + 255) / 256), 256, 0, stream>>>((float*)dego, 6000);
    k_zero<<<dim3((65536 + 255) / 256), 256, 0, stream>>>(hg, 65536);
    k_zero<<<dim3((65536 + 255) / 256), 256, 0, stream>>>(psum, 65536);

    // graph normalization + CSR build + weight transpose
    k_deg<<<dim3((E_ + 255) / 256), 256, 0, stream>>>(src, dst, dego, degi);
    k_norm<<<dim3((NN + 255) / 256), 256, 0, stream>>>(dego, degi, wout, win);
    k_scan<<<1, 512, 0, stream>>>(degi, ioff);
    k_fill<<<dim3((E_ + 255) / 256), 256, 0, stream>>>(src, dst, wout, win, ioff, cur, csrc, csrw);
    k_prepw<<<256, 256, 0, stream>>>(W1, wt1h);
    k_prepw<<<256, 256, 0, stream>>>(W2, wt2h);

    // scalar conv of input feature (all B), layer-0 pooling from it
    k_agg_scalar<<<dim3((NN + 63) / 64, B_), 64, 0, stream>>>(inp, ioff, csrc, csrw, avec);
    k_pool0<<<B_, 256, 0, stream>>>(avec, W0, b0, hg);

    dim3 gridNB(NN, CBH);
    dim3 gridGemm(C_ / GN, (CB * NN) / GM);

    for (int c = 0; c < nchunk; ++c) {
        int b0g = c * CB;

        // layer 1: fused expand+agg -> xB (bf16); MFMA gemm + fused pool -> xA (bf16)
        k_agg_l1<<<gridNB, 64, 0, stream>>>(avec, ioff, csrc, csrw, W0, b0, xB, b0g);
        k_gemm_mfma<1><<<gridGemm, 256, 0, stream>>>(xB, wt1h, b1, xAbf, psum, pmax);
        k_pool_combine<<<CB, 256, 0, stream>>>(psum, pmax, hg, b0g);

        // layer 2: bf16 gather agg -> xB; MFMA gemm, pool only (no C write)
        k_agg_bf<<<gridNB, 64, 0, stream>>>(xAbf, ioff, csrc, csrw, xB, QBH);
        k_gemm_mfma<0><<<gridGemm, 256, 0, stream>>>(xB, wt2h, b2, nullptr, psum, pmax);
        k_pool_combine<<<CB, 256, 0, stream>>>(psum, pmax, hg, b0g);
    }

    // head
    k_embed<<<B_, 128, 0, stream>>>(inp, We, emb);
    k_mlp1<<<B_, 512, 0, stream>>>(emb, hg, Wh1, bh1, h1);
    k_mlp2<<<B_, 256, 0, stream>>>(h1, Wh2, bh2, h2);
    k_out<<<B_, 256, 0, stream>>>(h2, Wh3, out);
}

// Round 8
// 623.734 us; speedup vs baseline: 1.0391x; 1.0391x over previous
//
#include <hip/hip_runtime.h>
#include <hip/hip_bf16.h>

// ---------------- problem constants ----------------
#define B_    128
#define NN    2000
#define C_    256
#define E_    64000
#define CIN   64
#define ROWST 2064   // CIN + NN
#define CEMB  128
#define HAZ1  512
#define HAZ2  256
#define FUSD  640    // CEMB + 2*C_

typedef unsigned short u16;
typedef __attribute__((ext_vector_type(8))) short short8;
typedef __attribute__((ext_vector_type(8))) unsigned short ush8;
typedef __attribute__((ext_vector_type(4))) float f32x4;

// ---------------- workspace layout (bytes) ----------------
static constexpr size_t OFF_DEGO = 0;        // int[2000]
static constexpr size_t OFF_DEGI = 8000;     // int[2000]
static constexpr size_t OFF_CUR  = 16000;    // int[2000]
static constexpr size_t OFF_WOUT = 24000;    // float[2000]
static constexpr size_t OFF_WIN  = 32000;    // float[2000]
static constexpr size_t OFF_IOFF = 40000;    // int[2001] (padded)
static constexpr size_t OFF_CSRC = 48192;    // int[64000]
static constexpr size_t OFF_CSRW = 304192;   // float[64000]
static constexpr size_t OFF_HG   = 560192;   // float[128*512]           -> 822336
static constexpr size_t OFF_H1   = 887872;   // float[128*512]           -> 1150016
static constexpr size_t OFF_PSUM = 1281088;  // float[128*256]           -> 1412160
static constexpr size_t OFF_PMAX = 1412160;  // float[128*256]           -> 1543232
static constexpr size_t OFF_A    = 1543232;  // float[2000*128] aT       -> 2567232
static constexpr size_t OFF_WT1H = 2567232;  // u16[256*256]             -> 2698304
static constexpr size_t OFF_WT2H = 2829376;  //                          -> 2960448
static constexpr size_t OFF_XT   = 3091520;  // float[2000*128] xT       -> 4115520
static constexpr size_t OFF_XBUF = 4194304;  // xB bf16 [CB*NN*C_], then xA bf16 [CB*NN*C_]

// ---------------- bf16 helpers (RNE) ----------------
__device__ __forceinline__ u16 f2bf(float f) {
    union { float f; unsigned u; } v; v.f = f;
    unsigned u = v.u;
    unsigned r = (u + 0x7FFFu + ((u >> 16) & 1u)) >> 16;
    return (u16)r;
}
__device__ __forceinline__ float bf2f(u16 h) {
    union { unsigned u; float f; } v; v.u = ((unsigned)h) << 16;
    return v.f;
}

// ---------------- merged init: zero deg counters, hg, psum/pmax ----------------
__global__ void k_init(int* __restrict__ deg3, float* __restrict__ hg,
                       float* __restrict__ ps) {
    int i = blockIdx.x * 256 + threadIdx.x;
    if (i < 6000) deg3[i] = 0;
    else if (i < 6000 + 65536) hg[i - 6000] = 0.f;
    else if (i < 6000 + 131072) ps[i - 71536] = 0.f;
}

__global__ void k_deg(const int* __restrict__ src, const int* __restrict__ dst,
                      int* __restrict__ dego, int* __restrict__ degi) {
    int e = blockIdx.x * 256 + threadIdx.x;
    if (e < E_) {
        atomicAdd(&dego[src[e]], 1);
        atomicAdd(&degi[dst[e]], 1);
    }
}

// exclusive scan of in-degrees -> ioff[0..NN]; also computes norm weights.
__global__ void k_scan_norm(const int* __restrict__ degi, const int* __restrict__ dego,
                            int* __restrict__ ioff, float* __restrict__ wout,
                            float* __restrict__ win) {
    __shared__ int part[512];
    int t = threadIdx.x;
    int base = t * 4;
    int v[4]; int s = 0;
#pragma unroll
    for (int i = 0; i < 4; i++) {
        int idx = base + i;
        v[i] = (idx < NN) ? degi[idx] : 0;
        if (idx < NN) {
            wout[idx] = rsqrtf(fmaxf((float)dego[idx], 1.f));
            win[idx]  = rsqrtf(fmaxf((float)v[i], 1.f));
        }
        s += v[i];
    }
    part[t] = s;
    __syncthreads();
    for (int o = 1; o < 512; o <<= 1) {
        int x = 0;
        if (t >= o) x = part[t - o];
        __syncthreads();
        part[t] += x;
        __syncthreads();
    }
    int run = (t == 0) ? 0 : part[t - 1];
#pragma unroll
    for (int i = 0; i < 4; i++) {
        int idx = base + i;
        if (idx <= NN) ioff[idx] = run;
        run += v[i];
    }
}

__global__ void k_fill(const int* __restrict__ src, const int* __restrict__ dst,
                       const float* __restrict__ wout, const float* __restrict__ win,
                       const int* __restrict__ ioff, int* __restrict__ cursor,
                       int* __restrict__ csrc, float* __restrict__ csrw) {
    int e = blockIdx.x * 256 + threadIdx.x;
    if (e < E_) {
        int d = dst[e];
        int s = src[e];
        int p = atomicAdd(&cursor[d], 1);
        int i = ioff[d] + p;
        csrc[i] = s;
        csrw[i] = wout[s] * win[d];
    }
}

// transpose both W (256x256) into bf16: T[n*256+k] = bf16(W[k*256+n]); 512 blocks
__global__ __launch_bounds__(256) void k_prepw2(
        const float* __restrict__ W1, const float* __restrict__ W2,
        u16* __restrict__ T1, u16* __restrict__ T2) {
    int which = blockIdx.x >> 8;
    int n = blockIdx.x & 255, k = threadIdx.x;
    const float* W = which ? W2 : W1;
    u16* T = which ? T2 : T1;
    T[n * 256 + k] = f2bf(W[(size_t)k * 256 + n]);
}

// transpose input node features to xT[n][b] (LDS 32x32 tile)
__global__ __launch_bounds__(256) void k_xt(
        const float* __restrict__ inp, float* __restrict__ xT) {
    __shared__ float tl[32][33];
    int tx = threadIdx.x & 31, ty = threadIdx.x >> 5;   // ty 0..7
    int n0 = blockIdx.x * 32, b0 = blockIdx.y * 32;
#pragma unroll
    for (int r = 0; r < 4; r++) {
        int b = b0 + ty + r * 8;
        int n = n0 + tx;
        if (n < NN) tl[tx][ty + r * 8] = inp[(size_t)b * ROWST + CIN + n];
    }
    __syncthreads();
#pragma unroll
    for (int r = 0; r < 4; r++) {
        int n = n0 + ty + r * 8;
        int b = b0 + tx;
        if (n < NN) xT[(size_t)n * B_ + b] = tl[ty + r * 8][tx];
    }
}

// scalar graph conv, batch across lanes: aT[n,b] = sum_e csrw * xT[src,b]
__global__ __launch_bounds__(64) void k_agg_scalar_t(
        const float* __restrict__ xT, const int* __restrict__ ioff,
        const int* __restrict__ csrc, const float* __restrict__ csrw,
        float* __restrict__ aT) {
    int n = blockIdx.x;
    int b = blockIdx.y * 64 + threadIdx.x;
    int e0 = ioff[n], e1 = ioff[n + 1];
    float acc0 = 0.f, acc1 = 0.f;
    int i = e0;
    for (; i + 2 <= e1; i += 2) {
        acc0 = fmaf(csrw[i],     xT[(size_t)csrc[i] * B_ + b],     acc0);
        acc1 = fmaf(csrw[i + 1], xT[(size_t)csrc[i + 1] * B_ + b], acc1);
    }
    if (i < e1) acc0 = fmaf(csrw[i], xT[(size_t)csrc[i] * B_ + b], acc0);
    aT[(size_t)n * B_ + b] = acc0 + acc1;
}

// layer-0 pooling straight from aT: x0[b,n,c] = relu(a*W0[c]+b0[c])
__global__ __launch_bounds__(256) void k_pool0(
        const float* __restrict__ aT, const float* __restrict__ W0,
        const float* __restrict__ b0, float* __restrict__ hg) {
    int b = blockIdx.x, c = threadIdx.x;
    float w0c = W0[c], b0c = b0[c];
    float s = 0.f, mx = 0.f;
    for (int n = 0; n < NN; n++) {
        float v = fmaxf(fmaf(aT[(size_t)n * B_ + b], w0c, b0c), 0.f);
        s += v;
        mx = fmaxf(mx, v);
    }
    hg[(size_t)b * 512 + c]       += s * (1.f / (float)NN);
    hg[(size_t)b * 512 + 256 + c] += mx;
}

// fused layer-0-expand + layer-1 aggregation, bf16 out, edge-loop unroll x2.
// wave serves 2 batch elems: lanes 0-31 -> bl=2*bp, lanes 32-63 -> 2*bp+1.
__global__ __launch_bounds__(64) void k_agg_l1(
        const float* __restrict__ aT, const int* __restrict__ ioff,
        const int* __restrict__ csrc, const float* __restrict__ csrw,
        const float* __restrict__ W0, const float* __restrict__ b0,
        u16* __restrict__ xout, int b0g) {
    int n = blockIdx.x, bp = blockIdx.y, t = threadIdx.x;
    int half = t >> 5, c8 = (t & 31) * 8;
    int bl = bp * 2 + half;
    int bg = b0g + bl;
    int e0 = ioff[n], e1 = ioff[n + 1];
    float w[8], bb[8], acca[8] = {}, accb[8] = {};
    {
        float4 w0 = *reinterpret_cast<const float4*>(&W0[c8]);
        float4 w1 = *reinterpret_cast<const float4*>(&W0[c8 + 4]);
        float4 v0 = *reinterpret_cast<const float4*>(&b0[c8]);
        float4 v1 = *reinterpret_cast<const float4*>(&b0[c8 + 4]);
        w[0]=w0.x; w[1]=w0.y; w[2]=w0.z; w[3]=w0.w;
        w[4]=w1.x; w[5]=w1.y; w[6]=w1.z; w[7]=w1.w;
        bb[0]=v0.x; bb[1]=v0.y; bb[2]=v0.z; bb[3]=v0.w;
        bb[4]=v1.x; bb[5]=v1.y; bb[6]=v1.z; bb[7]=v1.w;
    }
    int i = e0;
    for (; i + 2 <= e1; i += 2) {
        float a0 = aT[(size_t)csrc[i] * B_ + bg],     we0 = csrw[i];
        float a1 = aT[(size_t)csrc[i + 1] * B_ + bg], we1 = csrw[i + 1];
#pragma unroll
        for (int j = 0; j < 8; j++) {
            acca[j] = fmaf(fmaxf(fmaf(a0, w[j], bb[j]), 0.f), we0, acca[j]);
            accb[j] = fmaf(fmaxf(fmaf(a1, w[j], bb[j]), 0.f), we1, accb[j]);
        }
    }
    if (i < e1) {
        float a0 = aT[(size_t)csrc[i] * B_ + bg], we0 = csrw[i];
#pragma unroll
        for (int j = 0; j < 8; j++)
            acca[j] = fmaf(fmaxf(fmaf(a0, w[j], bb[j]), 0.f), we0, acca[j]);
    }
    ush8 o;
#pragma unroll
    for (int j = 0; j < 8; j++) o[j] = f2bf(acca[j] + accb[j]);
    *reinterpret_cast<ush8*>(&xout[((size_t)bl * NN + n) * C_ + c8]) = o;
}

// layer-2 aggregation, bf16 in/out, 2 bl per wave, 16B/lane gathers, unroll x4.
// XCD-locality swizzle (verified round 3: over-fetch eliminated).
__global__ __launch_bounds__(64) void k_agg_bf(
        const u16* __restrict__ xin, const int* __restrict__ ioff,
        const int* __restrict__ csrc, const float* __restrict__ csrw,
        u16* __restrict__ xout, int QBH) {
    int l = blockIdx.x + NN * blockIdx.y;   // HW linear workgroup id (x fastest)
    int xcd = l & 7, slot = l >> 3;
    int q = slot / NN;
    int bp = xcd * QBH + q;
    int n = slot - q * NN;
    int t = threadIdx.x;
    int half = t >> 5, c8 = (t & 31) * 8;
    int bl = bp * 2 + half;
    int e0 = ioff[n], e1 = ioff[n + 1];
    const u16* xb = xin + (size_t)bl * NN * C_ + c8;
    float acca[8] = {}, accb[8] = {}, accc[8] = {}, accd[8] = {};
    int i = e0;
    for (; i + 4 <= e1; i += 4) {
        int s0 = csrc[i];     float w0 = csrw[i];
        int s1 = csrc[i + 1]; float w1 = csrw[i + 1];
        int s2 = csrc[i + 2]; float w2 = csrw[i + 2];
        int s3 = csrc[i + 3]; float w3 = csrw[i + 3];
        ush8 v0 = *reinterpret_cast<const ush8*>(&xb[(size_t)s0 * C_]);
        ush8 v1 = *reinterpret_cast<const ush8*>(&xb[(size_t)s1 * C_]);
        ush8 v2 = *reinterpret_cast<const ush8*>(&xb[(size_t)s2 * C_]);
        ush8 v3 = *reinterpret_cast<const ush8*>(&xb[(size_t)s3 * C_]);
#pragma unroll
        for (int j = 0; j < 8; j++) {
            acca[j] = fmaf(bf2f(v0[j]), w0, acca[j]);
            accb[j] = fmaf(bf2f(v1[j]), w1, accb[j]);
            accc[j] = fmaf(bf2f(v2[j]), w2, accc[j]);
            accd[j] = fmaf(bf2f(v3[j]), w3, accd[j]);
        }
    }
    for (; i < e1; ++i) {
        int s0 = csrc[i]; float w0 = csrw[i];
        ush8 v0 = *reinterpret_cast<const ush8*>(&xb[(size_t)s0 * C_]);
#pragma unroll
        for (int j = 0; j < 8; j++) acca[j] = fmaf(bf2f(v0[j]), w0, acca[j]);
    }
    ush8 o;
#pragma unroll
    for (int j = 0; j < 8; j++)
        o[j] = f2bf((acca[j] + accb[j]) + (accc[j] + accd[j]));
    *reinterpret_cast<ush8*>(&xout[((size_t)bl * NN + n) * C_ + c8]) = o;
}

// ---------------- MFMA GEMM (bf16, 1 pass, reg double-buffer) + fused pool ---
// C = relu(A @ W + bias); pool (sum,max) per (bl, col) into psum/pmax atomics.
// OUT: 0 = pool only (no C write), 1 = write C as bf16.
#define GM 128
#define GN 128
#define GK 32
#define LDP 40   // padded u16 row stride (80 B) -> 2-way banks max on ds_read_b128

template<int OUT>
__global__ __launch_bounds__(256) void k_gemm_mfma(
        const u16* __restrict__ Abf, const u16* __restrict__ WTh,
        const float* __restrict__ bias,
        u16* __restrict__ Cbf, float* __restrict__ psum, float* __restrict__ pmax) {
    __shared__ u16 Ah[GM * LDP];
    __shared__ u16 Bh[GN * LDP];
    __shared__ float lsum[2][2][GN];
    __shared__ float lmax[2][2][GN];
    int tid  = threadIdx.x;
    int lane = tid & 63, wave = tid >> 6;
    int wm = wave >> 1, wn = wave & 1;
    int n0 = blockIdx.x * GN;
    int m0 = blockIdx.y * GM;
    int blk = lane >> 4, rr = lane & 15;
    int sr0 = tid >> 2, sseg = (tid & 3) * 8;   // staging row / k-seg
    int sr1 = sr0 + 64;

    f32x4 acc[4][4] = {};

    // prologue: prefetch k-tile 0 into registers
    ush8 va0 = *reinterpret_cast<const ush8*>(&Abf[(size_t)(m0 + sr0) * 256 + sseg]);
    ush8 vb0 = *reinterpret_cast<const ush8*>(&WTh[(size_t)(n0 + sr0) * 256 + sseg]);
    ush8 va1 = *reinterpret_cast<const ush8*>(&Abf[(size_t)(m0 + sr1) * 256 + sseg]);
    ush8 vb1 = *reinterpret_cast<const ush8*>(&WTh[(size_t)(n0 + sr1) * 256 + sseg]);

#pragma unroll
    for (int kk = 0; kk < 8; kk++) {
        *reinterpret_cast<ush8*>(&Ah[sr0 * LDP + sseg]) = va0;
        *reinterpret_cast<ush8*>(&Bh[sr0 * LDP + sseg]) = vb0;
        *reinterpret_cast<ush8*>(&Ah[sr1 * LDP + sseg]) = va1;
        *reinterpret_cast<ush8*>(&Bh[sr1 * LDP + sseg]) = vb1;
        __syncthreads();
        if (kk < 7) {   // prefetch next k-tile while MFMA runs
            int k0n = (kk + 1) * GK;
            va0 = *reinterpret_cast<const ush8*>(&Abf[(size_t)(m0 + sr0) * 256 + k0n + sseg]);
            vb0 = *reinterpret_cast<const ush8*>(&WTh[(size_t)(n0 + sr0) * 256 + k0n + sseg]);
            va1 = *reinterpret_cast<const ush8*>(&Abf[(size_t)(m0 + sr1) * 256 + k0n + sseg]);
            vb1 = *reinterpret_cast<const ush8*>(&WTh[(size_t)(n0 + sr1) * 256 + k0n + sseg]);
        }
        short8 af[4], bf[4];
#pragma unroll
        for (int mr = 0; mr < 4; mr++)
            af[mr] = *reinterpret_cast<const short8*>(
                &Ah[(wm * 64 + mr * 16 + rr) * LDP + blk * 8]);
#pragma unroll
        for (int nr = 0; nr < 4; nr++)
            bf[nr] = *reinterpret_cast<const short8*>(
                &Bh[(wn * 64 + nr * 16 + rr) * LDP + blk * 8]);
#pragma unroll
        for (int mr = 0; mr < 4; mr++)
#pragma unroll
            for (int nr = 0; nr < 4; nr++)
                acc[mr][nr] = __builtin_amdgcn_mfma_f32_16x16x32_bf16(
                    af[mr], bf[nr], acc[mr][nr], 0, 0, 0);
        __syncthreads();
    }

    // epilogue: bias + relu, optional bf16 store, fused (sum,max) pool
    int bl0   = m0 / NN;
    int split = (bl0 + 1) * NN - m0;   // local rows >= split belong to bl0+1

    float s_lo[4] = {}, s_hi[4] = {}, m_lo[4] = {}, m_hi[4] = {};
#pragma unroll
    for (int nr = 0; nr < 4; nr++) {
        int col = n0 + wn * 64 + nr * 16 + rr;
        float bs = bias[col];
#pragma unroll
        for (int mr = 0; mr < 4; mr++) {
            int rl = wm * 64 + mr * 16 + blk * 4;
#pragma unroll
            for (int j = 0; j < 4; j++) {
                float v = fmaxf(acc[mr][nr][j] + bs, 0.f);
                if (OUT == 1)
                    Cbf[(size_t)(m0 + rl + j) * 256 + col] = f2bf(v);
                bool second = (rl + j) >= split;
                s_lo[nr] += second ? 0.f : v;
                s_hi[nr] += second ? v : 0.f;
                m_lo[nr] = second ? m_lo[nr] : fmaxf(m_lo[nr], v);
                m_hi[nr] = second ? fmaxf(m_hi[nr], v) : m_hi[nr];
            }
        }
    }
#pragma unroll
    for (int nr = 0; nr < 4; nr++) {
        s_lo[nr] += __shfl_xor(s_lo[nr], 16); s_lo[nr] += __shfl_xor(s_lo[nr], 32);
        s_hi[nr] += __shfl_xor(s_hi[nr], 16); s_hi[nr] += __shfl_xor(s_hi[nr], 32);
        m_lo[nr] = fmaxf(m_lo[nr], __shfl_xor(m_lo[nr], 16));
        m_lo[nr] = fmaxf(m_lo[nr], __shfl_xor(m_lo[nr], 32));
        m_hi[nr] = fmaxf(m_hi[nr], __shfl_xor(m_hi[nr], 16));
        m_hi[nr] = fmaxf(m_hi[nr], __shfl_xor(m_hi[nr], 32));
    }
    if (lane < 16) {
#pragma unroll
        for (int nr = 0; nr < 4; nr++) {
            int cl = wn * 64 + nr * 16 + lane;
            lsum[0][wm][cl] = s_lo[nr];
            lsum[1][wm][cl] = s_hi[nr];
            lmax[0][wm][cl] = m_lo[nr];
            lmax[1][wm][cl] = m_hi[nr];
        }
    }
    __syncthreads();
    {
        int seg = tid >> 7, cl = tid & 127;
        if (!(seg == 1 && split >= GM)) {
            float s = lsum[seg][0][cl] + lsum[seg][1][cl];
            float m = fmaxf(lmax[seg][0][cl], lmax[seg][1][cl]);
            int blx = bl0 + seg;
            atomicAdd(&psum[blx * C_ + n0 + cl], s);
            atomicMax((unsigned int*)&pmax[blx * C_ + n0 + cl], __float_as_uint(m));
        }
    }
}

// combine fused-pool results into hg, then reset psum/pmax for next use
__global__ __launch_bounds__(256) void k_pool_combine(
        float* __restrict__ psum, float* __restrict__ pmax,
        float* __restrict__ hg, int b0g) {
    int bl = blockIdx.x, c = threadIdx.x;
    float s = psum[bl * C_ + c];
    float m = pmax[bl * C_ + c];
    psum[bl * C_ + c] = 0.f;
    pmax[bl * C_ + c] = 0.f;
    size_t b = b0g + bl;
    hg[b * 512 + c]       += s * (1.f / (float)NN);
    hg[b * 512 + 256 + c] += m;
}

// head stage 1: embed (inline) + fusion + mlp1
__global__ __launch_bounds__(512) void k_mlp1f(
        const float* __restrict__ inp, const float* __restrict__ We,
        const float* __restrict__ hg, const float* __restrict__ Wh1,
        const float* __restrict__ bh1, float* __restrict__ h1) {
    __shared__ float fus[FUSD];
    int b = blockIdx.x, j = threadIdx.x;
    if (j < CEMB) {
        const float* row = inp + (size_t)b * ROWST;
        float a = 0.f;
        for (int k = 0; k < CIN; k++) a += row[k] * We[k * CEMB + j];
        fus[j] = fmaxf(a, 0.f);
    }
    fus[CEMB + j] = hg[(size_t)b * 512 + j];
    __syncthreads();
    float a = bh1[j];
    for (int k = 0; k < FUSD; k++) a += fus[k] * Wh1[(size_t)k * HAZ1 + j];
    h1[(size_t)b * HAZ1 + j] = fmaxf(a, 0.f);
}

// head stage 2: mlp2 + output dot
__global__ __launch_bounds__(256) void k_mlp2out(
        const float* __restrict__ h1, const float* __restrict__ Wh2,
        const float* __restrict__ bh2, const float* __restrict__ Wh3,
        float* __restrict__ out) {
    __shared__ float f2[HAZ1];
    __shared__ float red[256];
    int b = blockIdx.x, j = threadIdx.x;
    f2[j]       = h1[(size_t)b * HAZ1 + j];
    f2[256 + j] = h1[(size_t)b * HAZ1 + 256 + j];
    __syncthreads();
    float a = bh2[j];
    for (int k = 0; k < HAZ1; k++) a += f2[k] * Wh2[(size_t)k * HAZ2 + j];
    red[j] = fmaxf(a, 0.f) * Wh3[j];
    __syncthreads();
    for (int o = 128; o > 0; o >>= 1) {
        if (j < o) red[j] += red[j + o];
        __syncthreads();
    }
    if (j == 0) out[b] = red[0];
}

// ---------------- launch ----------------
extern "C" void kernel_launch(void* const* d_in, const int* in_sizes, int n_in,
                              void* d_out, int out_size, void* d_ws, size_t ws_size,
                              hipStream_t stream) {
    const float* inp = (const float*)d_in[0];
    const int*   src = (const int*)d_in[1];
    const int*   dst = (const int*)d_in[2];
    const float* W0  = (const float*)d_in[3];
    const float* b0  = (const float*)d_in[4];
    const float* W1  = (const float*)d_in[5];
    const float* b1  = (const float*)d_in[6];
    const float* W2  = (const float*)d_in[7];
    const float* b2  = (const float*)d_in[8];
    const float* We  = (const float*)d_in[9];
    const float* Wh1 = (const float*)d_in[10];
    const float* bh1 = (const float*)d_in[11];
    const float* Wh2 = (const float*)d_in[12];
    const float* bh2 = (const float*)d_in[13];
    const float* Wh3 = (const float*)d_in[14];
    float* out = (float*)d_out;

    char* ws = (char*)d_ws;
    int*   dego = (int*)(ws + OFF_DEGO);
    int*   degi = (int*)(ws + OFF_DEGI);
    int*   cur  = (int*)(ws + OFF_CUR);
    float* wout = (float*)(ws + OFF_WOUT);
    float* win  = (float*)(ws + OFF_WIN);
    int*   ioff = (int*)(ws + OFF_IOFF);
    int*   csrc = (int*)(ws + OFF_CSRC);
    float* csrw = (float*)(ws + OFF_CSRW);
    float* hg   = (float*)(ws + OFF_HG);
    float* h1   = (float*)(ws + OFF_H1);
    float* psum = (float*)(ws + OFF_PSUM);
    float* pmax = (float*)(ws + OFF_PMAX);
    float* aT   = (float*)(ws + OFF_A);
    float* xT   = (float*)(ws + OFF_XT);
    u16*   wt1h = (u16*)(ws + OFF_WT1H);
    u16*   wt2h = (u16*)(ws + OFF_WT2H);

    // ---- choose batch-chunk size CB ----
    const size_t perb = (size_t)NN * C_ * 4;   // two bf16 x buffers per batch elem
    int CB = 128;
    while (CB > 16 && OFF_XBUF + (size_t)CB * perb > ws_size) CB >>= 1;
    int nchunk = B_ / CB;
    int CBH = CB / 2;
    int QBH = CBH / 8;

    u16* xB   = (u16*)(ws + OFF_XBUF);                              // agg out (GEMM A)
    u16* xAbf = (u16*)(ws + OFF_XBUF + (size_t)CB * NN * C_ * 2);   // bf16 x1

    // init + graph build + weight transpose + feature transpose
    k_init<<<dim3(536), 256, 0, stream>>>(dego, hg, psum);
    k_deg<<<dim3((E_ + 255) / 256), 256, 0, stream>>>(src, dst, dego, degi);
    k_scan_norm<<<1, 512, 0, stream>>>(degi, dego, ioff, wout, win);
    k_fill<<<dim3((E_ + 255) / 256), 256, 0, stream>>>(src, dst, wout, win, ioff, cur, csrc, csrw);
    k_prepw2<<<dim3(512), 256, 0, stream>>>(W1, W2, wt1h, wt2h);
    k_xt<<<dim3(63, 4), 256, 0, stream>>>(inp, xT);

    // scalar conv of input feature (all B, batch across lanes), layer-0 pooling
    k_agg_scalar_t<<<dim3(NN, 2), 64, 0, stream>>>(xT, ioff, csrc, csrw, aT);
    k_pool0<<<B_, 256, 0, stream>>>(aT, W0, b0, hg);

    dim3 gridNB(NN, CBH);
    dim3 gridGemm(C_ / GN, (CB * NN) / GM);

    for (int c = 0; c < nchunk; ++c) {
        int b0g = c * CB;

        // layer 1: fused expand+agg -> xB (bf16); MFMA gemm + fused pool -> xA (bf16)
        k_agg_l1<<<gridNB, 64, 0, stream>>>(aT, ioff, csrc, csrw, W0, b0, xB, b0g);
        k_gemm_mfma<1><<<gridGemm, 256, 0, stream>>>(xB, wt1h, b1, xAbf, psum, pmax);
        k_pool_combine<<<CB, 256, 0, stream>>>(psum, pmax, hg, b0g);

        // layer 2: bf16 gather agg -> xB; MFMA gemm, pool only (no C write)
        k_agg_bf<<<gridNB, 64, 0, stream>>>(xAbf, ioff, csrc, csrw, xB, QBH);
        k_gemm_mfma<0><<<gridGemm, 256, 0, stream>>>(xB, wt2h, b2, nullptr, psum, pmax);
        k_pool_combine<<<CB, 256, 0, stream>>>(psum, pmax, hg, b0g);
    }

    // head
    k_mlp1f<<<B_, 512, 0, stream>>>(inp, We, hg, Wh1, bh1, h1);
    k_mlp2out<<<B_, 256, 0, stream>>>(h1, Wh2, bh2, Wh3, out);
}